// Round 9
// baseline (140.483 us; speedup 1.0000x reference)
//
#include <hip/hip_runtime.h>

typedef short bf16x8 __attribute__((ext_vector_type(8)));
typedef ushort u16x4 __attribute__((ext_vector_type(4)));
typedef float f32x4 __attribute__((ext_vector_type(4)));

__device__ __forceinline__ ushort f2b(float f) {
    uint u = __builtin_bit_cast(uint, f);
    uint r = (u + 0x7fffu + ((u >> 16) & 1u)) >> 16;
    return (ushort)r;
}
__device__ __forceinline__ float b2f(ushort s) {
    uint u = ((uint)s) << 16;
    return __builtin_bit_cast(float, u);
}
__device__ __forceinline__ uint cvt_pk(float a, float b) {
    uint r;
    asm("v_cvt_pk_bf16_f32 %0, %1, %2" : "=v"(r) : "v"(a), "v"(b));
    return r;
}

// ---------------- prep: weights -> bf16, PRE-SWIZZLED rows (for LDS-staged B-frags) ----
__global__ __launch_bounds__(128) void prep_kernel(
        const float* __restrict__ w_q, const float* __restrict__ w_k,
        const float* __restrict__ w_v, const float* __restrict__ w_g,
        const float* __restrict__ w_o,
        ushort* __restrict__ wall, ushort* __restrict__ wo) {
    int row = blockIdx.x, col = threadIdx.x;
    int cs = col ^ ((row & 7) << 3);
    if (row < 512) {
        float val;
        if (row < 128)      val = w_q[row * 128 + col];
        else if (row < 256) val = w_k[(row - 128) * 128 + col];
        else if (row < 384) val = w_v[(row - 256) * 128 + col];
        else                val = w_g[(row - 384) * 128 + col];
        wall[row * 128 + cs] = f2b(val);
    } else {
        int r = row - 512;
        wo[r * 128 + cs] = f2b(w_o[r * 128 + col]);
    }
}

// ---------------- LayerNorm + pair-bias ----------------
// h stored bf16 PRE-SWIZZLED; biasQ[h][q][k] f32 (natural layout).
__global__ __launch_bounds__(256) void ln_bias_kernel(
        const float* __restrict__ x, const float* __restrict__ w_ln,
        const float* __restrict__ b_ln, const float* __restrict__ w_b,
        ushort* __restrict__ h, float* __restrict__ biasQ) {
    int row = blockIdx.x * 4 + (threadIdx.x >> 6);
    int lane = threadIdx.x & 63;
    float2 v = reinterpret_cast<const float2*>(x + (size_t)row * 128)[lane];
    float s = v.x + v.y;
    float sq = v.x * v.x + v.y * v.y;
#pragma unroll
    for (int off = 32; off >= 1; off >>= 1) {
        s += __shfl_xor(s, off);
        sq += __shfl_xor(sq, off);
    }
    float mean = s * (1.0f / 128.0f);
    float var = sq * (1.0f / 128.0f) - mean * mean;
    float rstd = rsqrtf(var + 1e-5f);
    int c0 = lane * 2;
    float h0 = (v.x - mean) * rstd * w_ln[c0] + b_ln[c0];
    float h1 = (v.y - mean) * rstd * w_ln[c0 + 1] + b_ln[c0 + 1];
    ushort2 o;
    o.x = f2b(h0);
    o.y = f2b(h1);
    reinterpret_cast<ushort2*>(h + (size_t)row * 128)[lane ^ ((row & 7) << 2)] = o;
    float p0 = h0 * w_b[c0]       + h1 * w_b[c0 + 1];
    float p1 = h0 * w_b[128 + c0] + h1 * w_b[128 + c0 + 1];
    float p2 = h0 * w_b[256 + c0] + h1 * w_b[256 + c0 + 1];
    float p3 = h0 * w_b[384 + c0] + h1 * w_b[384 + c0 + 1];
#pragma unroll
    for (int off = 32; off >= 1; off >>= 1) {
        p0 += __shfl_xor(p0, off);
        p1 += __shfl_xor(p1, off);
        p2 += __shfl_xor(p2, off);
        p3 += __shfl_xor(p3, off);
    }
    if (lane < 4) {
        float val = (lane == 0) ? p0 : (lane == 1) ? p1 : (lane == 2) ? p2 : p3;
        // row = i*256 + j -> bias[h][q=i][k=j]
        biasQ[(size_t)lane * 65536 + (size_t)(row >> 8) * 256 + (row & 255)] = val;
    }
}

// ---------------- projections: 128 m-rows/block, y-loop over q/k/v/g ----------------
// q -> [bh][p][32]; k -> [bh][p][32] with 16B-chunk XOR swizzle;
// v -> [bh][d][p] with 16B-chunk XOR swizzle; g row-major.
__global__ __launch_bounds__(256) void proj_kernel(
        const ushort* __restrict__ h, const ushort* __restrict__ wall,
        ushort* __restrict__ qp, ushort* __restrict__ kp,
        ushort* __restrict__ vt, ushort* __restrict__ g) {
    __shared__ ushort walls[16384];   // 128 rows x 128 cols bf16 = 32KB (per-y stage)
    int m0 = blockIdx.x * 128;
    int tid = threadIdx.x, w = tid >> 6, lane = tid & 63;
    int lo = lane & 15, hi = lane >> 4;
    bf16x8 a[2][4];
#pragma unroll
    for (int rh = 0; rh < 2; ++rh) {
        int arow = m0 + rh * 64 + w * 16 + lo;
#pragma unroll
        for (int ks = 0; ks < 4; ++ks)
            a[rh][ks] = *(const bf16x8*)(h + (size_t)arow * 128 +
                                         ((ks * 32 + hi * 8) ^ ((arow & 7) << 3)));
    }
    int bb = m0 >> 8;
#pragma unroll 1
    for (int y = 0; y < 4; ++y) {
        __syncthreads();
        for (int idx = tid; idx < 2048; idx += 256)
            ((float4*)walls)[idx] = ((const float4*)(wall + (size_t)y * 16384))[idx];
        __syncthreads();
#pragma unroll
        for (int nt = 0; nt < 8; ++nt) {
            int lr = nt * 16 + lo;
            bf16x8 bf[4];
#pragma unroll
            for (int ks = 0; ks < 4; ++ks)
                bf[ks] = *(const bf16x8*)(walls + lr * 128 +
                                          ((ks * 32 + hi * 8) ^ ((lr & 7) << 3)));
#pragma unroll
            for (int rh = 0; rh < 2; ++rh) {
                f32x4 acc = {0.f, 0.f, 0.f, 0.f};
#pragma unroll
                for (int ks = 0; ks < 4; ++ks)
                    acc = __builtin_amdgcn_mfma_f32_16x16x32_bf16(a[rh][ks], bf[ks],
                                                                  acc, 0, 0, 0);
                int d = nt * 16 + lo, head = d >> 5, dh = d & 31;
                int pbm = (m0 & 255) + rh * 64 + w * 16 + hi * 4;
                int mrow = m0 + rh * 64 + w * 16 + hi * 4;
                size_t base = ((size_t)(bb * 4 + head)) * 8192;
                if (y == 0) {
#pragma unroll
                    for (int r = 0; r < 4; ++r)
                        qp[base + (pbm + r) * 32 + dh] =
                            f2b(acc[r] * 0.17677669529663687f);
                } else if (y == 1) {
                    // k with 16B-chunk swizzle: chunk' = (dh>>3) ^ ((p>>1)&3)
#pragma unroll
                    for (int r = 0; r < 4; ++r) {
                        int p = pbm + r;
                        int ch = (dh >> 3) ^ ((p >> 1) & 3);
                        kp[base + p * 32 + (ch << 3) + (dh & 7)] = f2b(acc[r]);
                    }
                } else if (y == 2) {
                    // vt[bh][dh][p], 16B-chunk swizzle: chunk' = (p>>3) ^ (dh&7)
                    u16x4 t4;
#pragma unroll
                    for (int r = 0; r < 4; ++r) t4[r] = f2b(acc[r]);
                    *(u16x4*)(vt + base + dh * 256 +
                              ((((pbm >> 3) ^ (dh & 7)) << 3) + (pbm & 7))) = t4;
                } else {
#pragma unroll
                    for (int r = 0; r < 4; ++r)
                        g[(size_t)(mrow + r) * 128 + nt * 16 + lo] =
                            f2b(1.0f / (1.0f + __expf(-acc[r])));
                }
            }
        }
    }
}

// ---------------- attention: one block per (b,head), 8 waves, K/V staged once ------
// Swapped-QK (S^T), no-max softmax (scores bounded ~|20| << 88), O^T epilogue.
__global__ __launch_bounds__(512, 6) void attn_kernel(
        const ushort* __restrict__ qp, const ushort* __restrict__ kp,
        const ushort* __restrict__ vt, const ushort* __restrict__ gm,
        const float* __restrict__ biasQ, ushort* __restrict__ og) {
    __shared__ ushort Ks[8192];        // [p 256][d 32], 16B-chunk swizzled
    __shared__ ushort Vs[8192];        // [d 32][k 256], 16B-chunk swizzled
    __shared__ ushort P[8][16 * 40];   // per-wave P[q 16][k 32] chunk, stride 40
    int bh = blockIdx.x;
    int b = bh >> 2, head = bh & 3;
    int tid = threadIdx.x, w = tid >> 6, lane = tid & 63;
    int lo = lane & 15, hi = lane >> 4;
    const ushort* kb = kp + (size_t)bh * 8192;
    const ushort* vb = vt + (size_t)bh * 8192;
    for (int idx = tid; idx < 1024; idx += 512) {
        ((float4*)Ks)[idx] = ((const float4*)kb)[idx];
        ((float4*)Vs)[idx] = ((const float4*)vb)[idx];
    }
    __syncthreads();
    ushort* pw = P[w];
    int vsw = (lo & 7);
    int kch = hi ^ ((lo >> 1) & 3);    // K chunk de-swizzle
#pragma unroll
    for (int qt = 0; qt < 2; ++qt) {
        int qrow = w * 32 + qt * 16 + lo;              // this lane's q
        bf16x8 qa = *(const bf16x8*)(qp + (size_t)bh * 8192 + qrow * 32 + hi * 8);
        const float* bp = biasQ + (size_t)head * 65536 + (size_t)qrow * 256 + hi * 4;
        float l = 0.f;
        f32x4 a0 = {0.f, 0.f, 0.f, 0.f}, a1 = {0.f, 0.f, 0.f, 0.f};
#pragma unroll
        for (int c = 0; c < 8; ++c) {
            // QK^T (swapped): S^T[k][q], lane holds q=lo, rows k = c*32 + {hi*4+r, 16+hi*4+r}
            bf16x8 kf0 = *(const bf16x8*)(Ks + (c * 32 + lo) * 32 + kch * 8);
            bf16x8 kf1 = *(const bf16x8*)(Ks + (c * 32 + 16 + lo) * 32 + kch * 8);
            f32x4 c0 = *(const f32x4*)(bp + c * 32);
            f32x4 c1 = *(const f32x4*)(bp + c * 32 + 16);
            f32x4 s0 = __builtin_amdgcn_mfma_f32_16x16x32_bf16(kf0, qa, c0, 0, 0, 0);
            f32x4 s1 = __builtin_amdgcn_mfma_f32_16x16x32_bf16(kf1, qa, c1, 0, 0, 0);
            // direct exp (no max subtraction, no loop-carried rescale)
            float p00 = __expf(s0[0]), p01 = __expf(s0[1]);
            float p02 = __expf(s0[2]), p03 = __expf(s0[3]);
            float p10 = __expf(s1[0]), p11 = __expf(s1[1]);
            float p12 = __expf(s1[2]), p13 = __expf(s1[3]);
            l += ((p00 + p01) + (p02 + p03)) + ((p10 + p11) + (p12 + p13));
            uint2 w0, w1;
            w0.x = cvt_pk(p00, p01); w0.y = cvt_pk(p02, p03);
            w1.x = cvt_pk(p10, p11); w1.y = cvt_pk(p12, p13);
            *(uint2*)(pw + lo * 40 + hi * 4)      = w0;
            *(uint2*)(pw + lo * 40 + 16 + hi * 4) = w1;
            // PV (O^T = V^T . P^T)
            bf16x8 pf = *(const bf16x8*)(pw + lo * 40 + hi * 8);
            bf16x8 v0 = *(const bf16x8*)(Vs + lo * 256 + (((c * 4 + hi) ^ vsw) << 3));
            bf16x8 v1 = *(const bf16x8*)(Vs + (16 + lo) * 256 + (((c * 4 + hi) ^ vsw) << 3));
            a0 = __builtin_amdgcn_mfma_f32_16x16x32_bf16(v0, pf, a0, 0, 0, 0);
            a1 = __builtin_amdgcn_mfma_f32_16x16x32_bf16(v1, pf, a1, 0, 0, 0);
        }
        l += __shfl_xor(l, 16);
        l += __shfl_xor(l, 32);
        float rl = 1.0f / l;
        // epilogue: lane holds O^T[d = dtile*16 + hi*4 + r][q=lo]
        size_t mr = (size_t)b * 256 + qrow;
        int e0 = head * 32 + hi * 4, e1 = e0 + 16;
        u16x4 g0 = *(const u16x4*)(gm + mr * 128 + e0);
        u16x4 g1 = *(const u16x4*)(gm + mr * 128 + e1);
        u16x4 o0, o1;
#pragma unroll
        for (int r = 0; r < 4; ++r) {
            o0[r] = f2b(a0[r] * rl * b2f(g0[r]));
            o1[r] = f2b(a1[r] * rl * b2f(g1[r]));
        }
        int sw = (lo & 7) << 3;   // (qrow&7)<<3, q0 multiple of 16
        *(u16x4*)(og + mr * 128 + (e0 ^ sw)) = o0;
        *(u16x4*)(og + mr * 128 + (e1 ^ sw)) = o1;
    }
}

// ---------------- out GEMM: out = og @ wo^T ----------------
__global__ __launch_bounds__(256) void out_kernel(
        const ushort* __restrict__ og, const ushort* __restrict__ wo,
        float* __restrict__ out) {
    __shared__ ushort wos[16384];   // 128x128 bf16 (pre-swizzled rows)
    int m0 = blockIdx.x * 64;
    for (int idx = threadIdx.x; idx < 2048; idx += 256)
        ((float4*)wos)[idx] = ((const float4*)wo)[idx];
    int tid = threadIdx.x, w = tid >> 6, lane = tid & 63;
    int lo = lane & 15, hi = lane >> 4;
    int arow = m0 + w * 16 + lo;
    bf16x8 oa[4];
#pragma unroll
    for (int ks = 0; ks < 4; ++ks)
        oa[ks] = *(const bf16x8*)(og + (size_t)arow * 128 +
                                  ((ks * 32 + hi * 8) ^ ((arow & 7) << 3)));
    __syncthreads();
    int mrow = m0 + w * 16 + hi * 4;
#pragma unroll
    for (int nt = 0; nt < 8; ++nt) {
        f32x4 acc = {0.f, 0.f, 0.f, 0.f};
        int lr = nt * 16 + lo;
#pragma unroll
        for (int ks = 0; ks < 4; ++ks) {
            bf16x8 bf = *(const bf16x8*)(wos + lr * 128 +
                                         ((ks * 32 + hi * 8) ^ ((lr & 7) << 3)));
            acc = __builtin_amdgcn_mfma_f32_16x16x32_bf16(oa[ks], bf, acc, 0, 0, 0);
        }
#pragma unroll
        for (int r = 0; r < 4; ++r)
            out[(size_t)(mrow + r) * 128 + nt * 16 + lo] = acc[r];
    }
}

extern "C" void kernel_launch(void* const* d_in, const int* in_sizes, int n_in,
                              void* d_out, int out_size, void* d_ws, size_t ws_size,
                              hipStream_t stream) {
    const float* x    = (const float*)d_in[0];
    const float* w_ln = (const float*)d_in[1];
    const float* b_ln = (const float*)d_in[2];
    const float* w_b  = (const float*)d_in[3];
    const float* w_q  = (const float*)d_in[4];
    const float* w_k  = (const float*)d_in[5];
    const float* w_v  = (const float*)d_in[6];
    const float* w_g  = (const float*)d_in[7];
    const float* w_o  = (const float*)d_in[8];
    float* out = (float*)d_out;

    char* ws = (char*)d_ws;
    const size_t MB16 = (size_t)65536 * 128 * sizeof(ushort);   // 16 MB
    ushort* h      = (ushort*)(ws + 0 * MB16);
    ushort* qp     = (ushort*)(ws + 1 * MB16);
    ushort* kp     = (ushort*)(ws + 2 * MB16);
    ushort* vt     = (ushort*)(ws + 3 * MB16);
    ushort* g      = (ushort*)(ws + 4 * MB16);
    ushort* og     = (ushort*)(ws + 5 * MB16);
    float*  biasQ  = (float*)(ws + 6 * MB16);                   // 1 MB
    ushort* wall   = (ushort*)(ws + 6 * MB16 + (size_t)65536 * 4 * 4);
    ushort* wo     = wall + 512 * 128;

    prep_kernel<<<640, 128, 0, stream>>>(w_q, w_k, w_v, w_g, w_o, wall, wo);
    ln_bias_kernel<<<65536 / 4, 256, 0, stream>>>(x, w_ln, b_ln, w_b, h, biasQ);
    proj_kernel<<<512, 256, 0, stream>>>(h, wall, qp, kp, vt, g);
    attn_kernel<<<1024, 512, 0, stream>>>(qp, kp, vt, g, biasQ, og);
    out_kernel<<<1024, 256, 0, stream>>>(og, wo, out);
}

// Round 10
// 124.777 us; speedup vs baseline: 1.1259x; 1.1259x over previous
//
#include <hip/hip_runtime.h>

typedef short bf16x8 __attribute__((ext_vector_type(8)));
typedef ushort u16x4 __attribute__((ext_vector_type(4)));
typedef float f32x4 __attribute__((ext_vector_type(4)));

__device__ __forceinline__ ushort f2b(float f) {
    uint u = __builtin_bit_cast(uint, f);
    uint r = (u + 0x7fffu + ((u >> 16) & 1u)) >> 16;
    return (ushort)r;
}
__device__ __forceinline__ float b2f(ushort s) {
    uint u = ((uint)s) << 16;
    return __builtin_bit_cast(float, u);
}
__device__ __forceinline__ uint cvt_pk(float a, float b) {
    uint r;
    asm("v_cvt_pk_bf16_f32 %0, %1, %2" : "=v"(r) : "v"(a), "v"(b));
    return r;
}

// ---------------- prep: weights -> bf16, PRE-SWIZZLED rows (for LDS-staged B-frags) ----
__global__ __launch_bounds__(128) void prep_kernel(
        const float* __restrict__ w_q, const float* __restrict__ w_k,
        const float* __restrict__ w_v, const float* __restrict__ w_g,
        const float* __restrict__ w_o,
        ushort* __restrict__ wall, ushort* __restrict__ wo) {
    int row = blockIdx.x, col = threadIdx.x;
    int cs = col ^ ((row & 7) << 3);
    if (row < 512) {
        float val;
        if (row < 128)      val = w_q[row * 128 + col];
        else if (row < 256) val = w_k[(row - 128) * 128 + col];
        else if (row < 384) val = w_v[(row - 256) * 128 + col];
        else                val = w_g[(row - 384) * 128 + col];
        wall[row * 128 + cs] = f2b(val);
    } else {
        int r = row - 512;
        wo[r * 128 + cs] = f2b(w_o[r * 128 + col]);
    }
}

// ---------------- LayerNorm + pair-bias ----------------
// h stored bf16 PRE-SWIZZLED; biasQ[h][q][k] f32 (natural layout).
__global__ __launch_bounds__(256) void ln_bias_kernel(
        const float* __restrict__ x, const float* __restrict__ w_ln,
        const float* __restrict__ b_ln, const float* __restrict__ w_b,
        ushort* __restrict__ h, float* __restrict__ biasQ) {
    int row = blockIdx.x * 4 + (threadIdx.x >> 6);
    int lane = threadIdx.x & 63;
    float2 v = reinterpret_cast<const float2*>(x + (size_t)row * 128)[lane];
    float s = v.x + v.y;
    float sq = v.x * v.x + v.y * v.y;
#pragma unroll
    for (int off = 32; off >= 1; off >>= 1) {
        s += __shfl_xor(s, off);
        sq += __shfl_xor(sq, off);
    }
    float mean = s * (1.0f / 128.0f);
    float var = sq * (1.0f / 128.0f) - mean * mean;
    float rstd = rsqrtf(var + 1e-5f);
    int c0 = lane * 2;
    float h0 = (v.x - mean) * rstd * w_ln[c0] + b_ln[c0];
    float h1 = (v.y - mean) * rstd * w_ln[c0 + 1] + b_ln[c0 + 1];
    ushort2 o;
    o.x = f2b(h0);
    o.y = f2b(h1);
    reinterpret_cast<ushort2*>(h + (size_t)row * 128)[lane ^ ((row & 7) << 2)] = o;
    float p0 = h0 * w_b[c0]       + h1 * w_b[c0 + 1];
    float p1 = h0 * w_b[128 + c0] + h1 * w_b[128 + c0 + 1];
    float p2 = h0 * w_b[256 + c0] + h1 * w_b[256 + c0 + 1];
    float p3 = h0 * w_b[384 + c0] + h1 * w_b[384 + c0 + 1];
#pragma unroll
    for (int off = 32; off >= 1; off >>= 1) {
        p0 += __shfl_xor(p0, off);
        p1 += __shfl_xor(p1, off);
        p2 += __shfl_xor(p2, off);
        p3 += __shfl_xor(p3, off);
    }
    if (lane < 4) {
        float val = (lane == 0) ? p0 : (lane == 1) ? p1 : (lane == 2) ? p2 : p3;
        // row = i*256 + j -> bias[h][q=i][k=j]
        biasQ[(size_t)lane * 65536 + (size_t)(row >> 8) * 256 + (row & 255)] = val;
    }
}

// ---------------- projections: single dispatch, y-loop over q/k/v/g (R8-proven) -----
// q -> [bh][p][32]; k -> [bh][p][32] with 16B-chunk XOR swizzle;
// v -> [bh][d][p] with 16B-chunk XOR swizzle; g row-major.
__global__ __launch_bounds__(256) void proj_kernel(
        const ushort* __restrict__ h, const ushort* __restrict__ wall,
        ushort* __restrict__ qp, ushort* __restrict__ kp,
        ushort* __restrict__ vt, ushort* __restrict__ g) {
    __shared__ ushort walls[16384];   // 128 rows x 128 cols bf16 = 32KB (per-y stage)
    int m0 = blockIdx.x * 64;
    int tid = threadIdx.x, w = tid >> 6, lane = tid & 63;
    int lo = lane & 15, hi = lane >> 4;
    int arow = m0 + w * 16 + lo;
    bf16x8 a[4];
#pragma unroll
    for (int ks = 0; ks < 4; ++ks)
        a[ks] = *(const bf16x8*)(h + (size_t)arow * 128 +
                                 ((ks * 32 + hi * 8) ^ ((arow & 7) << 3)));
    int bb = m0 >> 8;
    int pbm = (m0 & 255) + w * 16 + hi * 4;
    int mrow = m0 + w * 16 + hi * 4;
#pragma unroll 1
    for (int y = 0; y < 4; ++y) {
        __syncthreads();
        for (int idx = tid; idx < 2048; idx += 256)
            ((float4*)walls)[idx] = ((const float4*)(wall + (size_t)y * 16384))[idx];
        __syncthreads();
#pragma unroll
        for (int nt = 0; nt < 8; ++nt) {
            f32x4 acc = {0.f, 0.f, 0.f, 0.f};
            int lr = nt * 16 + lo;
#pragma unroll
            for (int ks = 0; ks < 4; ++ks) {
                bf16x8 bf = *(const bf16x8*)(walls + lr * 128 +
                                             ((ks * 32 + hi * 8) ^ ((lr & 7) << 3)));
                acc = __builtin_amdgcn_mfma_f32_16x16x32_bf16(a[ks], bf, acc, 0, 0, 0);
            }
            int d = nt * 16 + lo, head = d >> 5, dh = d & 31;
            size_t base = ((size_t)(bb * 4 + head)) * 8192;
            if (y == 0) {
#pragma unroll
                for (int r = 0; r < 4; ++r)
                    qp[base + (pbm + r) * 32 + dh] =
                        f2b(acc[r] * 0.17677669529663687f);
            } else if (y == 1) {
                // k with 16B-chunk swizzle: chunk' = (dh>>3) ^ ((p>>1)&3)
#pragma unroll
                for (int r = 0; r < 4; ++r) {
                    int p = pbm + r;
                    int ch = (dh >> 3) ^ ((p >> 1) & 3);
                    kp[base + p * 32 + (ch << 3) + (dh & 7)] = f2b(acc[r]);
                }
            } else if (y == 2) {
                // vt[bh][dh][p], 16B-chunk swizzle: chunk' = (p>>3) ^ (dh&7)
                u16x4 t4;
#pragma unroll
                for (int r = 0; r < 4; ++r) t4[r] = f2b(acc[r]);
                *(u16x4*)(vt + base + dh * 256 +
                          ((((pbm >> 3) ^ (dh & 7)) << 3) + (pbm & 7))) = t4;
            } else {
#pragma unroll
                for (int r = 0; r < 4; ++r)
                    g[(size_t)(mrow + r) * 128 + nt * 16 + lo] =
                        f2b(1.0f / (1.0f + __expf(-acc[r])));
            }
        }
    }
}

// ---------------- attention: one block per (b,head), 8 waves, K/V staged once ------
// Swapped-QK (S^T), no-max softmax (scores bounded ~|20| << 88), O^T epilogue.
__global__ __launch_bounds__(512, 6) void attn_kernel(
        const ushort* __restrict__ qp, const ushort* __restrict__ kp,
        const ushort* __restrict__ vt, const ushort* __restrict__ gm,
        const float* __restrict__ biasQ, ushort* __restrict__ og) {
    __shared__ ushort Ks[8192];        // [p 256][d 32], 16B-chunk swizzled
    __shared__ ushort Vs[8192];        // [d 32][k 256], 16B-chunk swizzled
    __shared__ ushort P[8][16 * 40];   // per-wave P[q 16][k 32] chunk, stride 40
    int bh = blockIdx.x;
    int b = bh >> 2, head = bh & 3;
    int tid = threadIdx.x, w = tid >> 6, lane = tid & 63;
    int lo = lane & 15, hi = lane >> 4;
    const ushort* kb = kp + (size_t)bh * 8192;
    const ushort* vb = vt + (size_t)bh * 8192;
    for (int idx = tid; idx < 1024; idx += 512) {
        ((float4*)Ks)[idx] = ((const float4*)kb)[idx];
        ((float4*)Vs)[idx] = ((const float4*)vb)[idx];
    }
    __syncthreads();
    ushort* pw = P[w];
    int vsw = (lo & 7);
    int kch = hi ^ ((lo >> 1) & 3);    // K chunk de-swizzle
#pragma unroll
    for (int qt = 0; qt < 2; ++qt) {
        int qrow = w * 32 + qt * 16 + lo;              // this lane's q
        bf16x8 qa = *(const bf16x8*)(qp + (size_t)bh * 8192 + qrow * 32 + hi * 8);
        const float* bp = biasQ + (size_t)head * 65536 + (size_t)qrow * 256 + hi * 4;
        float l = 0.f;
        f32x4 a0 = {0.f, 0.f, 0.f, 0.f}, a1 = {0.f, 0.f, 0.f, 0.f};
#pragma unroll
        for (int c = 0; c < 8; ++c) {
            // QK^T (swapped): S^T[k][q], lane holds q=lo, rows k = c*32 + {hi*4+r, 16+hi*4+r}
            bf16x8 kf0 = *(const bf16x8*)(Ks + (c * 32 + lo) * 32 + kch * 8);
            bf16x8 kf1 = *(const bf16x8*)(Ks + (c * 32 + 16 + lo) * 32 + kch * 8);
            f32x4 c0 = *(const f32x4*)(bp + c * 32);
            f32x4 c1 = *(const f32x4*)(bp + c * 32 + 16);
            f32x4 s0 = __builtin_amdgcn_mfma_f32_16x16x32_bf16(kf0, qa, c0, 0, 0, 0);
            f32x4 s1 = __builtin_amdgcn_mfma_f32_16x16x32_bf16(kf1, qa, c1, 0, 0, 0);
            // direct exp (no max subtraction, no loop-carried rescale)
            float p00 = __expf(s0[0]), p01 = __expf(s0[1]);
            float p02 = __expf(s0[2]), p03 = __expf(s0[3]);
            float p10 = __expf(s1[0]), p11 = __expf(s1[1]);
            float p12 = __expf(s1[2]), p13 = __expf(s1[3]);
            l += ((p00 + p01) + (p02 + p03)) + ((p10 + p11) + (p12 + p13));
            uint2 w0, w1;
            w0.x = cvt_pk(p00, p01); w0.y = cvt_pk(p02, p03);
            w1.x = cvt_pk(p10, p11); w1.y = cvt_pk(p12, p13);
            *(uint2*)(pw + lo * 40 + hi * 4)      = w0;
            *(uint2*)(pw + lo * 40 + 16 + hi * 4) = w1;
            // PV (O^T = V^T . P^T)
            bf16x8 pf = *(const bf16x8*)(pw + lo * 40 + hi * 8);
            bf16x8 v0 = *(const bf16x8*)(Vs + lo * 256 + (((c * 4 + hi) ^ vsw) << 3));
            bf16x8 v1 = *(const bf16x8*)(Vs + (16 + lo) * 256 + (((c * 4 + hi) ^ vsw) << 3));
            a0 = __builtin_amdgcn_mfma_f32_16x16x32_bf16(v0, pf, a0, 0, 0, 0);
            a1 = __builtin_amdgcn_mfma_f32_16x16x32_bf16(v1, pf, a1, 0, 0, 0);
        }
        l += __shfl_xor(l, 16);
        l += __shfl_xor(l, 32);
        float rl = 1.0f / l;
        // epilogue: lane holds O^T[d = dtile*16 + hi*4 + r][q=lo]
        size_t mr = (size_t)b * 256 + qrow;
        int e0 = head * 32 + hi * 4, e1 = e0 + 16;
        u16x4 g0 = *(const u16x4*)(gm + mr * 128 + e0);
        u16x4 g1 = *(const u16x4*)(gm + mr * 128 + e1);
        u16x4 o0, o1;
#pragma unroll
        for (int r = 0; r < 4; ++r) {
            o0[r] = f2b(a0[r] * rl * b2f(g0[r]));
            o1[r] = f2b(a1[r] * rl * b2f(g1[r]));
        }
        int sw = (lo & 7) << 3;   // (qrow&7)<<3, q0 multiple of 16
        *(u16x4*)(og + mr * 128 + (e0 ^ sw)) = o0;
        *(u16x4*)(og + mr * 128 + (e1 ^ sw)) = o1;
    }
}

// ---------------- out GEMM: out = og @ wo^T ----------------
__global__ __launch_bounds__(256) void out_kernel(
        const ushort* __restrict__ og, const ushort* __restrict__ wo,
        float* __restrict__ out) {
    __shared__ ushort wos[16384];   // 128x128 bf16 (pre-swizzled rows)
    int m0 = blockIdx.x * 64;
    for (int idx = threadIdx.x; idx < 2048; idx += 256)
        ((float4*)wos)[idx] = ((const float4*)wo)[idx];
    int tid = threadIdx.x, w = tid >> 6, lane = tid & 63;
    int lo = lane & 15, hi = lane >> 4;
    int arow = m0 + w * 16 + lo;
    bf16x8 oa[4];
#pragma unroll
    for (int ks = 0; ks < 4; ++ks)
        oa[ks] = *(const bf16x8*)(og + (size_t)arow * 128 +
                                  ((ks * 32 + hi * 8) ^ ((arow & 7) << 3)));
    __syncthreads();
    int mrow = m0 + w * 16 + hi * 4;
#pragma unroll
    for (int nt = 0; nt < 8; ++nt) {
        f32x4 acc = {0.f, 0.f, 0.f, 0.f};
        int lr = nt * 16 + lo;
#pragma unroll
        for (int ks = 0; ks < 4; ++ks) {
            bf16x8 bf = *(const bf16x8*)(wos + lr * 128 +
                                         ((ks * 32 + hi * 8) ^ ((lr & 7) << 3)));
            acc = __builtin_amdgcn_mfma_f32_16x16x32_bf16(oa[ks], bf, acc, 0, 0, 0);
        }
#pragma unroll
        for (int r = 0; r < 4; ++r)
            out[(size_t)(mrow + r) * 128 + nt * 16 + lo] = acc[r];
    }
}

extern "C" void kernel_launch(void* const* d_in, const int* in_sizes, int n_in,
                              void* d_out, int out_size, void* d_ws, size_t ws_size,
                              hipStream_t stream) {
    const float* x    = (const float*)d_in[0];
    const float* w_ln = (const float*)d_in[1];
    const float* b_ln = (const float*)d_in[2];
    const float* w_b  = (const float*)d_in[3];
    const float* w_q  = (const float*)d_in[4];
    const float* w_k  = (const float*)d_in[5];
    const float* w_v  = (const float*)d_in[6];
    const float* w_g  = (const float*)d_in[7];
    const float* w_o  = (const float*)d_in[8];
    float* out = (float*)d_out;

    char* ws = (char*)d_ws;
    const size_t MB16 = (size_t)65536 * 128 * sizeof(ushort);   // 16 MB
    ushort* h      = (ushort*)(ws + 0 * MB16);
    ushort* qp     = (ushort*)(ws + 1 * MB16);
    ushort* kp     = (ushort*)(ws + 2 * MB16);
    ushort* vt     = (ushort*)(ws + 3 * MB16);
    ushort* g      = (ushort*)(ws + 4 * MB16);
    ushort* og     = (ushort*)(ws + 5 * MB16);
    float*  biasQ  = (float*)(ws + 6 * MB16);                   // 1 MB
    ushort* wall   = (ushort*)(ws + 6 * MB16 + (size_t)65536 * 4 * 4);
    ushort* wo     = wall + 512 * 128;

    prep_kernel<<<640, 128, 0, stream>>>(w_q, w_k, w_v, w_g, w_o, wall, wo);
    ln_bias_kernel<<<65536 / 4, 256, 0, stream>>>(x, w_ln, b_ln, w_b, h, biasQ);
    proj_kernel<<<1024, 256, 0, stream>>>(h, wall, qp, kp, vt, g);
    attn_kernel<<<1024, 512, 0, stream>>>(qp, kp, vt, g, biasQ, og);
    out_kernel<<<1024, 256, 0, stream>>>(og, wo, out);
}

// Round 11
// 111.481 us; speedup vs baseline: 1.2601x; 1.1193x over previous
//
#include <hip/hip_runtime.h>

typedef short bf16x8 __attribute__((ext_vector_type(8)));
typedef ushort u16x4 __attribute__((ext_vector_type(4)));
typedef float f32x4 __attribute__((ext_vector_type(4)));

__device__ __forceinline__ ushort f2b(float f) {
    uint u = __builtin_bit_cast(uint, f);
    uint r = (u + 0x7fffu + ((u >> 16) & 1u)) >> 16;
    return (ushort)r;
}
__device__ __forceinline__ float b2f(ushort s) {
    uint u = ((uint)s) << 16;
    return __builtin_bit_cast(float, u);
}
__device__ __forceinline__ uint cvt_pk(float a, float b) {
    uint r;
    asm("v_cvt_pk_bf16_f32 %0, %1, %2" : "=v"(r) : "v"(a), "v"(b));
    return r;
}

// ---------------- prep: weights -> bf16, PRE-SWIZZLED rows (for LDS-staged B-frags) ----
__global__ __launch_bounds__(128) void prep_kernel(
        const float* __restrict__ w_q, const float* __restrict__ w_k,
        const float* __restrict__ w_v, const float* __restrict__ w_g,
        const float* __restrict__ w_o,
        ushort* __restrict__ wall, ushort* __restrict__ wo) {
    int row = blockIdx.x, col = threadIdx.x;
    int cs = col ^ ((row & 7) << 3);
    if (row < 512) {
        float val;
        if (row < 128)      val = w_q[row * 128 + col];
        else if (row < 256) val = w_k[(row - 128) * 128 + col];
        else if (row < 384) val = w_v[(row - 256) * 128 + col];
        else                val = w_g[(row - 384) * 128 + col];
        wall[row * 128 + cs] = f2b(val);
    } else {
        int r = row - 512;
        wo[r * 128 + cs] = f2b(w_o[r * 128 + col]);
    }
}

// ---------------- LayerNorm + pair-bias ----------------
// h stored bf16 PRE-SWIZZLED; biasT[h][k][q] f32 (TRANSPOSED for coalesced attn reads).
__global__ __launch_bounds__(256) void ln_bias_kernel(
        const float* __restrict__ x, const float* __restrict__ w_ln,
        const float* __restrict__ b_ln, const float* __restrict__ w_b,
        ushort* __restrict__ h, float* __restrict__ biasT) {
    int row = blockIdx.x * 4 + (threadIdx.x >> 6);
    int lane = threadIdx.x & 63;
    float2 v = reinterpret_cast<const float2*>(x + (size_t)row * 128)[lane];
    float s = v.x + v.y;
    float sq = v.x * v.x + v.y * v.y;
#pragma unroll
    for (int off = 32; off >= 1; off >>= 1) {
        s += __shfl_xor(s, off);
        sq += __shfl_xor(sq, off);
    }
    float mean = s * (1.0f / 128.0f);
    float var = sq * (1.0f / 128.0f) - mean * mean;
    float rstd = rsqrtf(var + 1e-5f);
    int c0 = lane * 2;
    float h0 = (v.x - mean) * rstd * w_ln[c0] + b_ln[c0];
    float h1 = (v.y - mean) * rstd * w_ln[c0 + 1] + b_ln[c0 + 1];
    ushort2 o;
    o.x = f2b(h0);
    o.y = f2b(h1);
    reinterpret_cast<ushort2*>(h + (size_t)row * 128)[lane ^ ((row & 7) << 2)] = o;
    float p0 = h0 * w_b[c0]       + h1 * w_b[c0 + 1];
    float p1 = h0 * w_b[128 + c0] + h1 * w_b[128 + c0 + 1];
    float p2 = h0 * w_b[256 + c0] + h1 * w_b[256 + c0 + 1];
    float p3 = h0 * w_b[384 + c0] + h1 * w_b[384 + c0 + 1];
#pragma unroll
    for (int off = 32; off >= 1; off >>= 1) {
        p0 += __shfl_xor(p0, off);
        p1 += __shfl_xor(p1, off);
        p2 += __shfl_xor(p2, off);
        p3 += __shfl_xor(p3, off);
    }
    if (lane < 4) {
        float val = (lane == 0) ? p0 : (lane == 1) ? p1 : (lane == 2) ? p2 : p3;
        // row = i*256 + j; q=i, k=j -> biasT[h][k][q]
        biasT[(size_t)lane * 65536 + (size_t)(row & 255) * 256 + (row >> 8)] = val;
    }
}

// ---------------- projections: single dispatch, y-loop over q/k/v/g (R8-proven) -----
// q -> [bh][p][32]; k -> [bh][p][32] with 16B-chunk XOR swizzle;
// v -> [bh][d][p] with 16B-chunk XOR swizzle; g row-major.
__global__ __launch_bounds__(256) void proj_kernel(
        const ushort* __restrict__ h, const ushort* __restrict__ wall,
        ushort* __restrict__ qp, ushort* __restrict__ kp,
        ushort* __restrict__ vt, ushort* __restrict__ g) {
    __shared__ ushort walls[16384];   // 128 rows x 128 cols bf16 = 32KB (per-y stage)
    int m0 = blockIdx.x * 64;
    int tid = threadIdx.x, w = tid >> 6, lane = tid & 63;
    int lo = lane & 15, hi = lane >> 4;
    int arow = m0 + w * 16 + lo;
    bf16x8 a[4];
#pragma unroll
    for (int ks = 0; ks < 4; ++ks)
        a[ks] = *(const bf16x8*)(h + (size_t)arow * 128 +
                                 ((ks * 32 + hi * 8) ^ ((arow & 7) << 3)));
    int bb = m0 >> 8;
    int pbm = (m0 & 255) + w * 16 + hi * 4;
    int mrow = m0 + w * 16 + hi * 4;
#pragma unroll 1
    for (int y = 0; y < 4; ++y) {
        __syncthreads();
        for (int idx = tid; idx < 2048; idx += 256)
            ((float4*)walls)[idx] = ((const float4*)(wall + (size_t)y * 16384))[idx];
        __syncthreads();
#pragma unroll
        for (int nt = 0; nt < 8; ++nt) {
            f32x4 acc = {0.f, 0.f, 0.f, 0.f};
            int lr = nt * 16 + lo;
#pragma unroll
            for (int ks = 0; ks < 4; ++ks) {
                bf16x8 bf = *(const bf16x8*)(walls + lr * 128 +
                                             ((ks * 32 + hi * 8) ^ ((lr & 7) << 3)));
                acc = __builtin_amdgcn_mfma_f32_16x16x32_bf16(a[ks], bf, acc, 0, 0, 0);
            }
            int d = nt * 16 + lo, head = d >> 5, dh = d & 31;
            size_t base = ((size_t)(bb * 4 + head)) * 8192;
            if (y == 0) {
#pragma unroll
                for (int r = 0; r < 4; ++r)
                    qp[base + (pbm + r) * 32 + dh] =
                        f2b(acc[r] * 0.17677669529663687f);
            } else if (y == 1) {
                // k with 16B-chunk swizzle: chunk' = (dh>>3) ^ ((p>>1)&3)
#pragma unroll
                for (int r = 0; r < 4; ++r) {
                    int p = pbm + r;
                    int ch = (dh >> 3) ^ ((p >> 1) & 3);
                    kp[base + p * 32 + (ch << 3) + (dh & 7)] = f2b(acc[r]);
                }
            } else if (y == 2) {
                // vt[bh][dh][p], 16B-chunk swizzle: chunk' = (p>>3) ^ (dh&7)
                u16x4 t4;
#pragma unroll
                for (int r = 0; r < 4; ++r) t4[r] = f2b(acc[r]);
                *(u16x4*)(vt + base + dh * 256 +
                          ((((pbm >> 3) ^ (dh & 7)) << 3) + (pbm & 7))) = t4;
            } else {
#pragma unroll
                for (int r = 0; r < 4; ++r)
                    g[(size_t)(mrow + r) * 128 + nt * 16 + lo] =
                        f2b(1.0f / (1.0f + __expf(-acc[r])));
            }
        }
    }
}

// ---------------- attention: 2048 blocks x 256 thr, dbuf-P, scalar biasT loads ------
// Swapped-QK (S^T), no-max softmax, O^T epilogue. LDS exactly 40KB -> 4 blocks/CU.
__global__ __launch_bounds__(256, 4) void attn_kernel(
        const ushort* __restrict__ qp, const ushort* __restrict__ kp,
        const ushort* __restrict__ vt, const ushort* __restrict__ gm,
        const float* __restrict__ biasT, ushort* __restrict__ og) {
    __shared__ ushort Ks[8192];        // [p 256][d 32], 16B-chunk swizzled
    __shared__ ushort Vs[8192];        // [d 32][k 256], 16B-chunk swizzled
    __shared__ ushort P[4][1024];      // per-wave P[q 16][k 32], dbuf x chunk-XOR
    int blk = blockIdx.x, bh = blk & 1023, hf = blk >> 10;
    int b = bh >> 2, head = bh & 3;
    int tid = threadIdx.x, w = tid >> 6, lane = tid & 63;
    int lo = lane & 15, hi = lane >> 4;
    const ushort* kb = kp + (size_t)bh * 8192;
    const ushort* vb = vt + (size_t)bh * 8192;
    for (int idx = tid; idx < 1024; idx += 256) {
        ((float4*)Ks)[idx] = ((const float4*)kb)[idx];
        ((float4*)Vs)[idx] = ((const float4*)vb)[idx];
    }
    __syncthreads();
    ushort* pw = P[w];
    int vsw = (lo & 7);
    int kch = hi ^ ((lo >> 1) & 3);    // K chunk de-swizzle
    // P addresses (ushort units): row stride 32, chunk' = chunk ^ (lo&3)
    int pw0 = lo * 32 + (((hi >> 1) ^ (lo & 3)) << 3) + ((hi & 1) << 2);
    int pw1 = lo * 32 + (((2 | (hi >> 1)) ^ (lo & 3)) << 3) + ((hi & 1) << 2);
    int prd = lo * 32 + ((hi ^ (lo & 3)) << 3);
#pragma unroll
    for (int qt = 0; qt < 2; ++qt) {
        int qrow = hf * 128 + w * 32 + qt * 16 + lo;   // this lane's q
        bf16x8 qa = *(const bf16x8*)(qp + (size_t)bh * 8192 + qrow * 32 + hi * 8);
        // scalar bias base: biasT[head][k][qrow], k = c*32 + hi*4 + r (+16)
        const float* btq = biasT + (size_t)head * 65536 + (size_t)(hi * 4) * 256 + qrow;
        float l = 0.f;
        f32x4 a0 = {0.f, 0.f, 0.f, 0.f}, a1 = {0.f, 0.f, 0.f, 0.f};
#pragma unroll
        for (int c = 0; c < 8; ++c) {
            // coalesced scalar C-operand loads (16 lanes hit one 64B segment each)
            f32x4 c0, c1;
#pragma unroll
            for (int r = 0; r < 4; ++r) {
                c0[r] = btq[(c * 32 + r) * 256];
                c1[r] = btq[(c * 32 + 16 + r) * 256];
            }
            // QK^T (swapped): S^T[k][q], lane holds q=lo, rows k = c*32 + {hi*4+r, 16+hi*4+r}
            bf16x8 kf0 = *(const bf16x8*)(Ks + (c * 32 + lo) * 32 + kch * 8);
            bf16x8 kf1 = *(const bf16x8*)(Ks + (c * 32 + 16 + lo) * 32 + kch * 8);
            f32x4 s0 = __builtin_amdgcn_mfma_f32_16x16x32_bf16(kf0, qa, c0, 0, 0, 0);
            f32x4 s1 = __builtin_amdgcn_mfma_f32_16x16x32_bf16(kf1, qa, c1, 0, 0, 0);
            // direct exp (no max subtraction; scores bounded << 88)
            float p00 = __expf(s0[0]), p01 = __expf(s0[1]);
            float p02 = __expf(s0[2]), p03 = __expf(s0[3]);
            float p10 = __expf(s1[0]), p11 = __expf(s1[1]);
            float p12 = __expf(s1[2]), p13 = __expf(s1[3]);
            l += ((p00 + p01) + (p02 + p03)) + ((p10 + p11) + (p12 + p13));
            uint2 w0, w1;
            w0.x = cvt_pk(p00, p01); w0.y = cvt_pk(p02, p03);
            w1.x = cvt_pk(p10, p11); w1.y = cvt_pk(p12, p13);
            // double-buffered P (breaks WAR serialization across c-iters)
            ushort* pb = pw + ((c & 1) << 9);
            *(uint2*)(pb + pw0) = w0;
            *(uint2*)(pb + pw1) = w1;
            // PV (O^T = V^T . P^T)
            bf16x8 pf = *(const bf16x8*)(pb + prd);
            bf16x8 v0 = *(const bf16x8*)(Vs + lo * 256 + (((c * 4 + hi) ^ vsw) << 3));
            bf16x8 v1 = *(const bf16x8*)(Vs + (16 + lo) * 256 + (((c * 4 + hi) ^ vsw) << 3));
            a0 = __builtin_amdgcn_mfma_f32_16x16x32_bf16(v0, pf, a0, 0, 0, 0);
            a1 = __builtin_amdgcn_mfma_f32_16x16x32_bf16(v1, pf, a1, 0, 0, 0);
        }
        l += __shfl_xor(l, 16);
        l += __shfl_xor(l, 32);
        float rl = 1.0f / l;
        // epilogue: lane holds O^T[d = dtile*16 + hi*4 + r][q=lo]
        size_t mr = (size_t)b * 256 + qrow;
        int e0 = head * 32 + hi * 4, e1 = e0 + 16;
        u16x4 g0 = *(const u16x4*)(gm + mr * 128 + e0);
        u16x4 g1 = *(const u16x4*)(gm + mr * 128 + e1);
        u16x4 o0, o1;
#pragma unroll
        for (int r = 0; r < 4; ++r) {
            o0[r] = f2b(a0[r] * rl * b2f(g0[r]));
            o1[r] = f2b(a1[r] * rl * b2f(g1[r]));
        }
        int sw = (lo & 7) << 3;   // (qrow&7)<<3, q0 multiple of 16
        *(u16x4*)(og + mr * 128 + (e0 ^ sw)) = o0;
        *(u16x4*)(og + mr * 128 + (e1 ^ sw)) = o1;
    }
}

// ---------------- out GEMM: out = og @ wo^T ----------------
__global__ __launch_bounds__(256) void out_kernel(
        const ushort* __restrict__ og, const ushort* __restrict__ wo,
        float* __restrict__ out) {
    __shared__ ushort wos[16384];   // 128x128 bf16 (pre-swizzled rows)
    int m0 = blockIdx.x * 64;
    for (int idx = threadIdx.x; idx < 2048; idx += 256)
        ((float4*)wos)[idx] = ((const float4*)wo)[idx];
    int tid = threadIdx.x, w = tid >> 6, lane = tid & 63;
    int lo = lane & 15, hi = lane >> 4;
    int arow = m0 + w * 16 + lo;
    bf16x8 oa[4];
#pragma unroll
    for (int ks = 0; ks < 4; ++ks)
        oa[ks] = *(const bf16x8*)(og + (size_t)arow * 128 +
                                  ((ks * 32 + hi * 8) ^ ((arow & 7) << 3)));
    __syncthreads();
    int mrow = m0 + w * 16 + hi * 4;
#pragma unroll
    for (int nt = 0; nt < 8; ++nt) {
        f32x4 acc = {0.f, 0.f, 0.f, 0.f};
        int lr = nt * 16 + lo;
#pragma unroll
        for (int ks = 0; ks < 4; ++ks) {
            bf16x8 bf = *(const bf16x8*)(wos + lr * 128 +
                                         ((ks * 32 + hi * 8) ^ ((lr & 7) << 3)));
            acc = __builtin_amdgcn_mfma_f32_16x16x32_bf16(oa[ks], bf, acc, 0, 0, 0);
        }
#pragma unroll
        for (int r = 0; r < 4; ++r)
            out[(size_t)(mrow + r) * 128 + nt * 16 + lo] = acc[r];
    }
}

extern "C" void kernel_launch(void* const* d_in, const int* in_sizes, int n_in,
                              void* d_out, int out_size, void* d_ws, size_t ws_size,
                              hipStream_t stream) {
    const float* x    = (const float*)d_in[0];
    const float* w_ln = (const float*)d_in[1];
    const float* b_ln = (const float*)d_in[2];
    const float* w_b  = (const float*)d_in[3];
    const float* w_q  = (const float*)d_in[4];
    const float* w_k  = (const float*)d_in[5];
    const float* w_v  = (const float*)d_in[6];
    const float* w_g  = (const float*)d_in[7];
    const float* w_o  = (const float*)d_in[8];
    float* out = (float*)d_out;

    char* ws = (char*)d_ws;
    const size_t MB16 = (size_t)65536 * 128 * sizeof(ushort);   // 16 MB
    ushort* h      = (ushort*)(ws + 0 * MB16);
    ushort* qp     = (ushort*)(ws + 1 * MB16);
    ushort* kp     = (ushort*)(ws + 2 * MB16);
    ushort* vt     = (ushort*)(ws + 3 * MB16);
    ushort* g      = (ushort*)(ws + 4 * MB16);
    ushort* og     = (ushort*)(ws + 5 * MB16);
    float*  biasT  = (float*)(ws + 6 * MB16);                   // 1 MB
    ushort* wall   = (ushort*)(ws + 6 * MB16 + (size_t)65536 * 4 * 4);
    ushort* wo     = wall + 512 * 128;

    prep_kernel<<<640, 128, 0, stream>>>(w_q, w_k, w_v, w_g, w_o, wall, wo);
    ln_bias_kernel<<<65536 / 4, 256, 0, stream>>>(x, w_ln, b_ln, w_b, h, biasT);
    proj_kernel<<<1024, 256, 0, stream>>>(h, wall, qp, kp, vt, g);
    attn_kernel<<<2048, 256, 0, stream>>>(qp, kp, vt, g, biasT, og);
    out_kernel<<<1024, 256, 0, stream>>>(og, wo, out);
}